// Round 2
// baseline (755.675 us; speedup 1.0000x reference)
//
#include <hip/hip_runtime.h>
#include <hip/hip_bf16.h>

#define H 128
#define H1 129
#define NSLAB (H1 * H1)          // 16641 slabs of 129 W1-rows
#define SLABSZ (H1 * 64)         // 8256 floats per slab
#define NBLK 512                 // 2 blocks/CU at <=256 VGPR
#define AV_FLOATS (NSLAB * 64)   // 1,065,024
#define PART_FLOATS (NBLK * 4096)

typedef __attribute__((ext_vector_type(8))) short short8;
typedef __attribute__((ext_vector_type(4))) float float4v;

__device__ __forceinline__ short bfb(float x) {
    return (short)__builtin_bit_cast(unsigned short, __float2bfloat16(x));
}

// k0: av[sl*64 + b] = a_h[b, sl/129] * v_h[b, sl%129]
__global__ void k0_av(const float* __restrict__ a, const float* __restrict__ v,
                      float* __restrict__ avf)
{
    int idx = blockIdx.x * 256 + threadIdx.x;
    if (idx >= AV_FLOATS) return;
    int sl = idx >> 6, b = idx & 63;
    int si = sl / H1, sj = sl % H1;
    float ah = (si == 0) ? 1.f : a[b * H + si - 1];
    float vh = (sj == 0) ? 1.f : v[b * H + sj - 1];
    avf[idx] = ah * vh;
}

// k1: per slab sl, D = t_h @ W1slab (bf16 MFMA, no LDS, register double-buffer),
//     y1 += av * D.  Wave w owns output cols [16w,16w+16), all 64 batch rows.
__global__ __launch_bounds__(256, 2) void k1_partial(
        const float* __restrict__ t, const float* __restrict__ W1,
        const float* __restrict__ avf, float* __restrict__ partials)
{
    const int tid  = threadIdx.x;
    const int w    = tid >> 6;
    const int lane = tid & 63;
    const int quad = lane >> 4;
    const int l15  = lane & 15;
    const int ncol = 16 * w + l15;

    // A fragments (t_h, bf16, loop-invariant): tf[mt][s]
    // A[m=l15 -> b=16mt+l15][k=32s+8quad+j], k in [0,128)
    short8 tf[4][4];
    #pragma unroll
    for (int mt = 0; mt < 4; ++mt) {
        int b = 16 * mt + l15;
        #pragma unroll
        for (int s = 0; s < 4; ++s) {
            short8 f;
            #pragma unroll
            for (int j = 0; j < 8; ++j) {
                int k = 32 * s + 8 * quad + j;
                float val = (k == 0) ? 1.0f : t[b * H + k - 1];
                f[j] = bfb(val);
            }
            tf[mt][s] = f;
        }
    }
    // tl[mt][r] = t_h[b=16mt+4quad+r][128] = t[b][127]  (k=128 handled in fp32)
    float4v tl[4];
    #pragma unroll
    for (int mt = 0; mt < 4; ++mt)
        #pragma unroll
        for (int r = 0; r < 4; ++r)
            tl[mt][r] = t[(16 * mt + 4 * quad + r) * H + 127];

    const int s0 = (int)(((long long)blockIdx.x * NSLAB) / NBLK);
    const int s1 = (int)(((long long)(blockIdx.x + 1) * NSLAB) / NBLK);
    const int niter = s1 - s0;

    // register double buffers
    float   fb[2][4][8];
    float4v avb[2][4];
    float   wl[2];

    auto LOADSLAB = [&](int sl, int p) __attribute__((always_inline)) {
        const float* Wb = W1 + (long long)sl * SLABSZ;
        #pragma unroll
        for (int s = 0; s < 4; ++s) {
            const float* rp = Wb + (32 * s + 8 * quad) * 64 + ncol;
            #pragma unroll
            for (int j = 0; j < 8; ++j) fb[p][s][j] = rp[j * 64];
        }
        wl[p] = Wb[128 * 64 + ncol];
        const float* ap = avf + sl * 64 + 4 * quad;
        #pragma unroll
        for (int mt = 0; mt < 4; ++mt)
            avb[p][mt] = *(const float4v*)(ap + 16 * mt);
    };

    const float4v vz = {0.f, 0.f, 0.f, 0.f};
    float4v y1[4] = {vz, vz, vz, vz};

    auto COMPUTE = [&](int p) __attribute__((always_inline)) {
        float4v D[4] = {vz, vz, vz, vz};
        #pragma unroll
        for (int s = 0; s < 4; ++s) {
            short8 Bf;
            #pragma unroll
            for (int j = 0; j < 8; ++j) Bf[j] = bfb(fb[p][s][j]);
            #pragma unroll
            for (int mt = 0; mt < 4; ++mt)
                D[mt] = __builtin_amdgcn_mfma_f32_16x16x32_bf16(tf[mt][s], Bf, D[mt], 0, 0, 0);
        }
        #pragma unroll
        for (int mt = 0; mt < 4; ++mt) {
            y1[mt] += avb[p][mt] * D[mt];
            y1[mt] += (avb[p][mt] * tl[mt]) * wl[p];
        }
    };

    LOADSLAB(s0, 0);
    int it = 0;
    for (; it + 2 <= niter; it += 2) {
        int n1 = s0 + it + 1;                       // always < s1 here
        int n2 = (it + 2 < niter) ? s0 + it + 2 : s1 - 1;  // clamp: dummy reload (cache-hit)
        LOADSLAB(n1, 1);
        COMPUTE(0);
        LOADSLAB(n2, 0);
        COMPUTE(1);
    }
    if (it < niter) COMPUTE(0);   // odd tail: slab already in buffer 0

    float* pp = partials + (long long)blockIdx.x * 4096;
    #pragma unroll
    for (int mt = 0; mt < 4; ++mt)
        #pragma unroll
        for (int r = 0; r < 4; ++r)
            pp[(16 * mt + 4 * quad + r) * 64 + ncol] = y1[mt][r];
}

// k2: reduce 512 partial buffers -> acc[4096], no atomics.
// 128 blocks; block bb owns cells [bb*32, bb*32+32); thread = (pg=tid>>5, c=tid&31)
__global__ void k2_reduce(const float* __restrict__ partials, float* __restrict__ acc)
{
    __shared__ float red[8][32];
    const int tid = threadIdx.x;
    const int c = tid & 31, pg = tid >> 5;
    const int cell = blockIdx.x * 32 + c;
    float s = 0.f;
    for (int p = pg; p < NBLK; p += 8)
        s += partials[p * 4096 + cell];
    red[pg][c] = s;
    __syncthreads();
    if (pg == 0) {
        float tot = 0.f;
        #pragma unroll
        for (int g = 0; g < 8; ++g) tot += red[g][c];
        acc[cell] = tot;
    }
}

// k3: bias+relu, layer2, layer3 (tiny: 64x64 -> 64x32 -> 64)
__global__ void k3_tail(const float* __restrict__ acc, const float* __restrict__ b1,
                        const float* __restrict__ W2, const float* __restrict__ b2,
                        const float* __restrict__ W3, const float* __restrict__ b3,
                        float* __restrict__ out)
{
    __shared__ float y1s[64 * 64];
    __shared__ float y2s[64 * 32];
    const int tid = threadIdx.x;

    for (int e = tid; e < 64 * 64; e += 256) {
        float x = acc[e] + b1[e & 63];
        y1s[e] = x > 0.f ? x : 0.f;
    }
    __syncthreads();
    for (int e = tid; e < 64 * 32; e += 256) {
        int b = e >> 5, h2 = e & 31;
        float s = b2[h2];
        #pragma unroll 8
        for (int h = 0; h < 64; ++h) s += y1s[b * 64 + h] * W2[h * 32 + h2];
        y2s[e] = s > 0.f ? s : 0.f;
    }
    __syncthreads();
    if (tid < 64) {
        float s = b3[0];
        #pragma unroll
        for (int h2 = 0; h2 < 32; ++h2) s += y2s[tid * 32 + h2] * W3[h2];
        out[tid] = s;
    }
}

extern "C" void kernel_launch(void* const* d_in, const int* in_sizes, int n_in,
                              void* d_out, int out_size, void* d_ws, size_t ws_size,
                              hipStream_t stream) {
    const float* v  = (const float*)d_in[0];
    const float* a  = (const float*)d_in[1];
    const float* t  = (const float*)d_in[2];
    const float* W1 = (const float*)d_in[3];
    const float* b1 = (const float*)d_in[4];
    const float* W2 = (const float*)d_in[5];
    const float* b2 = (const float*)d_in[6];
    const float* W3 = (const float*)d_in[7];
    const float* b3 = (const float*)d_in[8];

    float* avf      = (float*)d_ws;                       // 4,260,096 floats
    float* partials = avf + AV_FLOATS;                    // 512*4096 floats
    float* acc      = partials + PART_FLOATS;             // 4096 floats

    hipLaunchKernelGGL(k0_av, dim3((AV_FLOATS + 255) / 256), dim3(256), 0, stream, a, v, avf);
    hipLaunchKernelGGL(k1_partial, dim3(NBLK), dim3(256), 0, stream, t, W1, avf, partials);
    hipLaunchKernelGGL(k2_reduce, dim3(128), dim3(256), 0, stream, partials, acc);
    hipLaunchKernelGGL(k3_tail, dim3(1), dim3(256), 0, stream,
                       acc, b1, W2, b2, W3, b3, (float*)d_out);
}